// Round 13
// baseline (185.964 us; speedup 1.0000x reference)
//
#include <hip/hip_runtime.h>
#include <hip/hip_bf16.h>

// InputProjection: shared LayerNorm + Q/K/V projections (fp32 in, fp32 out).
// R13: occupancy re-shape. R9-R12 proved single-block lockstep phasing is
// serialized DS+MFMA (~33% MfmaUtil, 1 block/CU, nothing fills stalls).
// New geometry: 128x128 tile, 4 waves (wave tile 64x64, acc=64 VGPR), BK=32,
// 2 LDS buffers = 32 KiB/block, __launch_bounds__(256,4) -> 4 blocks/CU
// (16 waves/CU). Cross-block TLP fills DS/barrier/vmcnt windows (m97/m114
// mechanism). 1 phase per K-tile: {8 ds_read; stage T+1 (4 gload_lds);
// lgkm(0); 16 MFMA; vmcnt(0); barrier} - same proven sync protocol.

#define HIDDEN 1024
#define NTOK   32768

typedef __bf16 bf16x8 __attribute__((ext_vector_type(8)));
typedef float  f32x4  __attribute__((ext_vector_type(4)));

#define GLOBAL_AS(p) ((const __attribute__((address_space(1))) void*)(p))
#define LDS_AS(p)    ((__attribute__((address_space(3))) void*)(p))

__device__ __forceinline__ unsigned short f2bf(float f) {
  union { float f; unsigned int i; } x; x.f = f;
  unsigned int r = x.i + 0x7FFFu + ((x.i >> 16) & 1u);   // RNE
  return (unsigned short)(r >> 16);
}

// ---------------- K1: LayerNorm (fp32 in, bf16 out) + weight cvt ----------------
__global__ __launch_bounds__(256) void ln_cvt_kernel(
    const float* __restrict__ x,
    const float* __restrict__ gamma,
    const float* __restrict__ beta,
    const float* __restrict__ wq,
    const float* __restrict__ wk,
    const float* __restrict__ wv,
    unsigned short* __restrict__ xn,
    unsigned short* __restrict__ wb) {
  const int bid = blockIdx.x;
  const int t   = threadIdx.x;
  if (bid < NTOK) {
    const size_t base = (size_t)bid * HIDDEN;
    const float4 v = ((const float4*)(x + base))[t];
    float s  = v.x + v.y + v.z + v.w;
    float s2 = v.x*v.x + v.y*v.y + v.z*v.z + v.w*v.w;
#pragma unroll
    for (int off = 32; off >= 1; off >>= 1) {
      s  += __shfl_xor(s,  off);
      s2 += __shfl_xor(s2, off);
    }
    __shared__ float red[8];
    const int w = t >> 6;
    if ((t & 63) == 0) { red[w] = s; red[4 + w] = s2; }
    __syncthreads();
    s  = red[0] + red[1] + red[2] + red[3];
    s2 = red[4] + red[5] + red[6] + red[7];
    const float mu   = s * (1.0f / HIDDEN);
    const float rstd = rsqrtf(s2 * (1.0f / HIDDEN) - mu * mu + 1e-5f);
    const float4 g  = ((const float4*)gamma)[t];
    const float4 bb = ((const float4*)beta)[t];
    ushort4 o;
    o.x = f2bf((v.x - mu) * rstd * g.x + bb.x);
    o.y = f2bf((v.y - mu) * rstd * g.y + bb.y);
    o.z = f2bf((v.z - mu) * rstd * g.z + bb.z);
    o.w = f2bf((v.w - mu) * rstd * g.w + bb.w);
    ((ushort4*)(xn + base))[t] = o;
  } else {
    const int b2 = bid - NTOK;           // 0..1535; 1024 wq, 256 wk, 256 wv
    const float* src;
    int off;
    if (b2 < 1024)      { src = wq; off = b2; }
    else if (b2 < 1280) { src = wk; off = b2 - 1024; }
    else                { src = wv; off = b2 - 1280; }
    const float4 v = ((const float4*)src)[off * 256 + t];
    ushort4 o;
    o.x = f2bf(v.x); o.y = f2bf(v.y); o.z = f2bf(v.z); o.w = f2bf(v.w);
    ((ushort4*)wb)[b2 * 256 + t] = o;
  }
}

// ---------------- K2: high-occupancy QKV GEMM ----------------
// 3072 blocks (256 M x 12 N), 256 threads (4 waves, 2M x 2N), wave tile 64x64.
__global__ __launch_bounds__(256, 4) void qkv_gemm(
    const unsigned short* __restrict__ xn,
    const unsigned short* __restrict__ wqb,
    const float* __restrict__ bq,
    const float* __restrict__ bk,
    const float* __restrict__ bv,
    float* __restrict__ out) {
  // A: [2 buf][128 rows][32 k], B same. 8192 elems each = 16 KiB; total 32 KiB.
  __shared__ unsigned short lds[16384];
  unsigned short* Alds = lds;
  unsigned short* Blds = lds + 8192;

  const int bid = blockIdx.x;
  const int swz = (bid & 7) * 384 + (bid >> 3);   // bijective: 3072 % 8 == 0
  const int mt  = swz / 12;
  const int nt  = swz % 12;                        // 12 consecutive share A-panel (L2)
  const int brow = mt * 128;

  const unsigned short* wbase; const float* biasptr;
  int segcol; size_t obase; int hg;
  if (nt < 8)        { wbase = wqb + (size_t)nt * 128 * HIDDEN;            biasptr = bq; segcol = nt * 128;        obase = 0u;        hg = 16; }
  else if (nt < 10)  { wbase = wqb + (size_t)(1024 + (nt - 8) * 128) * HIDDEN;  biasptr = bk; segcol = (nt - 8) * 128;  obase = 33554432u; hg = 4; }
  else               { wbase = wqb + (size_t)(1280 + (nt - 10) * 128) * HIDDEN; biasptr = bv; segcol = (nt - 10) * 128; obase = 41943040u; hg = 4; }

  const int t = threadIdx.x;
  const int w = t >> 6, lane = t & 63;
  const int wm = w >> 1, wn = w & 1;               // wave tile: rows wm*64, cols wn*64
  const int l15 = lane & 15, hi = lane >> 4;

  // staging: wave w covers rows w*32..w*32+31 (2 instr x 16 rows).
  // lane: row = w*32 + (lane>>2), granule = (lane&3) ^ ((row>>1)&3) (64B-seg coalesced)
  const int sr  = w * 32 + (lane >> 2);
  const int scg = ((lane & 3) ^ ((lane >> 3) & 3)) * 8;
  const unsigned short* aST = xn    + (size_t)(brow + sr) * HIDDEN + scg;
  const unsigned short* bST = wbase + (size_t)sr * HIDDEN + scg;
  const int ldsq = w * 1024;   // wave-uniform elems; HW adds lane*16B

  // ds_read: addr = buf*4096 + row*32 + (hi ^ ((row>>1)&3))*8 ; row%16 == l15
  const int rdx  = (hi ^ ((l15 >> 1) & 3)) * 8;
  const int rowA = wm * 64 + l15;
  const int rowB = wn * 64 + l15;

  f32x4 acc[4][4];
#pragma unroll
  for (int m = 0; m < 4; ++m)
#pragma unroll
    for (int n = 0; n < 4; ++n) acc[m][n] = (f32x4){0.f, 0.f, 0.f, 0.f};
  bf16x8 a[4], b[4];

#define STA(BUF, KT) do {                                                       \
    unsigned short* _d = Alds + (BUF) * 4096 + ldsq;                            \
    const unsigned short* _s = aST + (size_t)((KT) * 32);                       \
    __builtin_amdgcn_global_load_lds(GLOBAL_AS(_s), LDS_AS(_d), 16, 0, 0);      \
    __builtin_amdgcn_global_load_lds(GLOBAL_AS(_s + 16 * HIDDEN), LDS_AS(_d + 512), 16, 0, 0); \
  } while (0)
#define STB(BUF, KT) do {                                                       \
    unsigned short* _d = Blds + (BUF) * 4096 + ldsq;                            \
    const unsigned short* _s = bST + (size_t)((KT) * 32);                       \
    __builtin_amdgcn_global_load_lds(GLOBAL_AS(_s), LDS_AS(_d), 16, 0, 0);      \
    __builtin_amdgcn_global_load_lds(GLOBAL_AS(_s + 16 * HIDDEN), LDS_AS(_d + 512), 16, 0, 0); \
  } while (0)
#define RD(BUF) do { _Pragma("unroll")                                          \
    for (int m = 0; m < 4; ++m)                                                 \
      a[m] = *(const bf16x8*)(Alds + (BUF) * 4096 + (rowA + m * 16) * 32 + rdx);\
    _Pragma("unroll")                                                           \
    for (int n = 0; n < 4; ++n)                                                 \
      b[n] = *(const bf16x8*)(Blds + (BUF) * 4096 + (rowB + n * 16) * 32 + rdx);\
  } while (0)
#define MMX do { _Pragma("unroll")                                              \
    for (int m = 0; m < 4; ++m)                                                 \
      _Pragma("unroll") for (int n = 0; n < 4; ++n)                             \
        acc[m][n] = __builtin_amdgcn_mfma_f32_16x16x32_bf16(a[m], b[n], acc[m][n], 0, 0, 0); \
  } while (0)
#define PIN __builtin_amdgcn_sched_barrier(0)

  // prologue: stage tile 0 into buf0, validate for all waves.
  STA(0, 0); STB(0, 0);
  asm volatile("s_waitcnt vmcnt(0)" ::: "memory");
  PIN;
  __builtin_amdgcn_s_barrier();
  PIN;

#pragma unroll 2
  for (int T = 0; T < 31; ++T) {
    const int buf = T & 1;
    RD(buf);                       // 8 ds_read_b128 (tile T)
    STA(buf ^ 1, T + 1);           // prefetch tile T+1 (buf^1: its tile T-1
    STB(buf ^ 1, T + 1);           //   reads drained at iter T-1's lgkm+bar)
    PIN;
    asm volatile("s_waitcnt lgkmcnt(0)" ::: "memory");
    PIN;
    MMX;                           // 16 MFMA on tile T
    asm volatile("s_waitcnt vmcnt(0)" ::: "memory");   // tile T+1 landed (all waves via barrier)
    PIN;
    __builtin_amdgcn_s_barrier();
    PIN;
  }
  // tail: tile 31, no stage.
  RD(1);
  asm volatile("s_waitcnt lgkmcnt(0)" ::: "memory");
  PIN;
  MMX;
  // all waves done reading LDS before epilogue overwrites it
  __builtin_amdgcn_s_barrier();
  PIN;

#undef STA
#undef STB
#undef RD
#undef MMX
#undef PIN

  // ---- epilogue: coalesced. Wave output = contiguous [64 tok][64 d] fp32.
  // Per 16-token chunk: acc+bias -> LDS (stride 84 f32, 2-way max) ->
  // float4 reads -> 1KB-contiguous stores. Per-wave-disjoint LDS regions.
  float* ep = (float*)lds;               // 4 waves x 16 x 84 f32 = 21504 B
  const int epb = w * 1344;
  const int headcol = segcol + wn * 64;
  const int gidx = headcol >> 6;
  const int tok0 = brow + wm * 64;
  const int b_ = tok0 >> 12;
  float* wout = out + obase + (size_t)(b_ * hg + gidx) * 262144u
                    + (size_t)(tok0 & 4095) * 64u;
  float biasv[4];
#pragma unroll
  for (int n = 0; n < 4; ++n) biasv[n] = biasptr[headcol + n * 16 + l15];

#pragma unroll
  for (int m = 0; m < 4; ++m) {
#pragma unroll
    for (int n = 0; n < 4; ++n)
#pragma unroll
      for (int j = 0; j < 4; ++j)
        ep[epb + (hi * 4 + j) * 84 + n * 16 + l15] = acc[m][n][j] + biasv[n];
    asm volatile("s_waitcnt lgkmcnt(0)" ::: "memory");
#pragma unroll
    for (int it = 0; it < 4; ++it) {
      const int r = it * 4 + hi;
      const float4 v = *(const float4*)(ep + epb + r * 84 + l15 * 4);
      *(float4*)(wout + (size_t)(m * 16 + r) * 64 + l15 * 4) = v;
    }
  }
}

extern "C" void kernel_launch(void* const* d_in, const int* in_sizes, int n_in,
                              void* d_out, int out_size, void* d_ws, size_t ws_size,
                              hipStream_t stream) {
  const float* x  = (const float*)d_in[0];
  const float* wq = (const float*)d_in[1];
  const float* wk = (const float*)d_in[2];
  const float* wv = (const float*)d_in[3];
  const float* bq = (const float*)d_in[4];
  const float* bk = (const float*)d_in[5];
  const float* bv = (const float*)d_in[6];
  const float* g  = (const float*)d_in[7];
  const float* be = (const float*)d_in[8];
  float* out = (float*)d_out;

  unsigned short* xn = (unsigned short*)d_ws;                          // 64 MiB
  unsigned short* wb = (unsigned short*)((char*)d_ws + (64u << 20));   // 3 MiB (wq|wk|wv bf16)

  ln_cvt_kernel<<<NTOK + 1536, 256, 0, stream>>>(x, g, be, wq, wk, wv, xn, wb);
  qkv_gemm<<<3072, 256, 0, stream>>>(xn, wb, bq, bk, bv, out);
}